// Round 6
// baseline (368.923 us; speedup 1.0000x reference)
//
#include <hip/hip_runtime.h>
#include <hip/hip_bf16.h>

#define NPTS  1048576
#define GRID  768
#define NTILE 8192   // NPTS / 128
#define C2    2.8853900817779268f   // 2*log2(e)

typedef __attribute__((ext_vector_type(8))) short  s16x8;
typedef __attribute__((ext_vector_type(4))) float  f32x4;

__device__ __forceinline__ unsigned short bf16r(float v) {
  unsigned u = __builtin_bit_cast(unsigned, v);
  return (unsigned short)((u + 0x7fffu + ((u >> 16) & 1u)) >> 16);
}
__device__ __forceinline__ unsigned pack_bf16x2(float lo, float hi) {
  __hip_bfloat162 h = __float22bfloat162_rn(float2{lo, hi});
  unsigned r;
  __builtin_memcpy(&r, &h, sizeof(r));
  return r;
}
// tanh(s) with bias pre-folded: s = acc + bias; bc = bias*C2
__device__ __forceinline__ float tanh_e(float acc, float bc) {
  float e = __builtin_amdgcn_exp2f(fmaf(acc, C2, bc));
  return 1.0f - 2.0f * __builtin_amdgcn_rcpf(1.0f + e);
}
__device__ __forceinline__ float sigm_fast(float x) {
  return __builtin_amdgcn_rcpf(1.0f + __builtin_amdgcn_exp2f(x * -1.4426950408889634f));
}
// k' permutation: position k' holds original column n_orig(k')
__device__ __forceinline__ int n_orig(int kp) {
  return ((kp >> 1) & 3) * 32 + (kp & 1) * 16 + (kp >> 3);
}

// ws layout (u16 units):
//  [0 .. 49152)        : Wt images, flat: ws[m*16384 + n*128 + k'] = bf16(W[n_orig(k')][n]), m=0..2 (W2,W3,W4)
//  [49152 .. 49920)    : 384 floats: w1x[128], w1y[128], b1[128], each in k'-order
//  [49920 .. 50944)    : b5f image: ws[49920 + kt*512 + lane*8 + e]
__global__ void prep_kernel(const float* __restrict__ W1, const float* __restrict__ b1,
                            const float* __restrict__ W2, const float* __restrict__ W3,
                            const float* __restrict__ W4, const float* __restrict__ W5,
                            unsigned short* __restrict__ ws)
{
  int tid = blockIdx.x * 256 + threadIdx.x;
  if (tid < 49152) {
    int m   = tid >> 14;
    int idx = tid & 16383;
    int n   = idx >> 7;
    int kp  = idx & 127;
    int k   = n_orig(kp);
    const float* W = (m == 0) ? W2 : (m == 1) ? W3 : W4;
    ws[(m << 14) + n * 128 + kp] = bf16r(W[k * 128 + n]);
  } else if (tid < 49536) {
    int i = tid - 49152;                 // 0..383
    float* wsf = (float*)(ws + 49152);
    int kp = i & 127;
    int j  = n_orig(kp);
    float v;
    if (i < 128)      v = W1[j];
    else if (i < 256) v = W1[128 + j];
    else              v = b1[j];
    wsf[i] = v;
  } else if (tid < 50560) {
    int idx = tid - 49536;               // 0..1023
    int e  = idx & 7;
    int l  = (idx >> 3) & 63;
    int kt = idx >> 9;
    int lg = l >> 4, lnl = l & 15;
    int no = ((e >> 1) & 3) * 32 + (e & 1) * 16 + kt * 4 + lg;
    unsigned short v = 0;
    if (lnl < 2) v = bf16r(W5[no * 2 + lnl]);
    ws[49920 + kt * 512 + l * 8 + e] = v;
  }
}

__global__ __launch_bounds__(256, 3)
void mlp_kernel(const float* __restrict__ xy, const float* __restrict__ Uin,
                const float* __restrict__ b2, const float* __restrict__ b3,
                const float* __restrict__ b4, const float* __restrict__ b5,
                const unsigned short* __restrict__ ws, float* __restrict__ out)
{
  __shared__ __align__(16) unsigned char hbuf[32768];  // 128 rows x 128 k' bf16

  const int tid  = threadIdx.x;
  const int lane = tid & 63;
  const int wid  = tid >> 6;   // 0..3 : column group of 32
  const int lg   = lane >> 4;  // 0..3
  const int ln   = lane & 15;
  const int c0   = tid & 15;   // layer-1 k'-chunk

  const float Uval = Uin[0];
  const float b5v  = (ln < 2) ? b5[ln] : 0.0f;

  // biases (folded with C2) for this thread's two columns per layer
  float bcr[3][2];
#pragma unroll
  for (int nt = 0; nt < 2; ++nt) {
    int n = wid * 32 + nt * 16 + ln;
    bcr[0][nt] = b2[n] * C2;
    bcr[1][nt] = b3[n] * C2;
    bcr[2][nt] = b4[n] * C2;
  }

  // layer-1 weights for this thread's k'-chunk c0
  const float* wsf = (const float*)(ws + 49152);
  float w1x[8], w1y[8], b1r[8];
#pragma unroll
  for (int t = 0; t < 8; ++t) {
    w1x[t] = wsf[c0 * 8 + t];
    w1y[t] = wsf[128 + c0 * 8 + t];
    b1r[t] = wsf[256 + c0 * 8 + t];
  }

  for (int tile = blockIdx.x; tile < NTILE; tile += GRID) {
    const int pbase = tile << 7;

    // ---- layer 1: h1 = tanh(xy@W1+b1) -> hbuf (k'-order, swizzled) ----
#pragma unroll
    for (int i = 0; i < 8; ++i) {
      int p = i * 16 + (tid >> 4);
      float2 v = ((const float2*)xy)[pbase + p];
      unsigned q[4];
#pragma unroll
      for (int t2 = 0; t2 < 4; ++t2) {
        float s0 = fmaf(v.x, w1x[2 * t2],     fmaf(v.y, w1y[2 * t2],     b1r[2 * t2]));
        float s1 = fmaf(v.x, w1x[2 * t2 + 1], fmaf(v.y, w1y[2 * t2 + 1], b1r[2 * t2 + 1]));
        float e0 = __builtin_amdgcn_exp2f(s0 * C2);
        float e1 = __builtin_amdgcn_exp2f(s1 * C2);
        float h0 = 1.0f - 2.0f * __builtin_amdgcn_rcpf(1.0f + e0);
        float h1 = 1.0f - 2.0f * __builtin_amdgcn_rcpf(1.0f + e1);
        q[t2] = pack_bf16x2(h0, h1);
      }
      unsigned byte = ((unsigned)(p * 256 + c0 * 16)) ^ ((unsigned)(p & 7) << 4);
      *(uint4*)(hbuf + byte) = uint4{q[0], q[1], q[2], q[3]};
    }
    __syncthreads();

    // ---- layers 2..4 ----
#pragma unroll
    for (int l = 0; l < 3; ++l) {
      // B-fragments for this wave's 32 columns, all K (held across mt)
      s16x8 B[2][4];
#pragma unroll
      for (int nt = 0; nt < 2; ++nt) {
        int n = wid * 32 + nt * 16 + ln;
#pragma unroll
        for (int kt = 0; kt < 4; ++kt)
          B[nt][kt] = *(const s16x8*)(ws + l * 16384 + n * 128 + kt * 32 + lg * 8);
      }

      unsigned pend[8][4];
#pragma unroll
      for (int mt = 0; mt < 8; ++mt) {
        s16x8 A[4];
#pragma unroll
        for (int kt = 0; kt < 4; ++kt) {
          int row = mt * 16 + ln;
          unsigned byte = ((unsigned)(row * 256 + kt * 64 + lg * 16)) ^ ((unsigned)(row & 7) << 4);
          A[kt] = *(const s16x8*)(hbuf + byte);
        }
        f32x4 acc0 = f32x4{0.f, 0.f, 0.f, 0.f};
        f32x4 acc1 = f32x4{0.f, 0.f, 0.f, 0.f};
#pragma unroll
        for (int kt = 0; kt < 4; ++kt) {
          acc0 = __builtin_amdgcn_mfma_f32_16x16x32_bf16(A[kt], B[0][kt], acc0, 0, 0, 0);
          acc1 = __builtin_amdgcn_mfma_f32_16x16x32_bf16(A[kt], B[1][kt], acc1, 0, 0, 0);
        }
#pragma unroll
        for (int r = 0; r < 4; ++r) {
          float t0 = tanh_e(acc0[r], bcr[l][0]);
          float t1 = tanh_e(acc1[r], bcr[l][1]);
          pend[mt][r] = pack_bf16x2(t0, t1);
        }
      }
      __syncthreads();   // all waves done reading hbuf
#pragma unroll
      for (int mt = 0; mt < 8; ++mt) {
#pragma unroll
        for (int r = 0; r < 4; ++r) {
          int row = mt * 16 + lg * 4 + r;
          unsigned byte = ((unsigned)(row * 256 + ln * 16 + wid * 4)) ^ ((unsigned)(row & 7) << 4);
          *(unsigned*)(hbuf + byte) = pend[mt][r];
        }
      }
      __syncthreads();   // writes visible
    }

    // ---- layer 5 + epilogue (each wave: rows wid*32 .. wid*32+31) ----
    f32x4 acc5[2];
#pragma unroll
    for (int m5 = 0; m5 < 2; ++m5) acc5[m5] = f32x4{0.f, 0.f, 0.f, 0.f};
#pragma unroll
    for (int m5 = 0; m5 < 2; ++m5)
#pragma unroll
      for (int kt = 0; kt < 4; ++kt) {
        s16x8 b5f = *(const s16x8*)(ws + 49920 + kt * 512 + lane * 8);
        int row = wid * 32 + m5 * 16 + ln;
        unsigned byte = ((unsigned)(row * 256 + kt * 64 + lg * 16)) ^ ((unsigned)(row & 7) << 4);
        s16x8 a = *(const s16x8*)(hbuf + byte);
        acc5[m5] = __builtin_amdgcn_mfma_f32_16x16x32_bf16(a, b5f, acc5[m5], 0, 0, 0);
      }
    if (ln < 2) {
#pragma unroll
      for (int m5 = 0; m5 < 2; ++m5)
#pragma unroll
        for (int r = 0; r < 4; ++r) {
          int p = pbase + wid * 32 + m5 * 16 + lg * 4 + r;
          float uh = acc5[m5][r] + b5v;
          float2 v = ((const float2*)xy)[p];
          float Bm = v.x * (1.0f - v.x) * v.y * (1.0f - v.y);
          if (ln == 0) {
            float psi = sigm_fast(50.0f * (v.x - 0.05f)) * sigm_fast(50.0f * (0.95f - v.x));
            out[p] = Uval * v.y * psi + Bm * uh;
          } else {
            out[NPTS + p] = Bm * uh;
          }
        }
    }
    __syncthreads();   // protect hbuf before next tile's layer-1 writes
  }
}

extern "C" void kernel_launch(void* const* d_in, const int* in_sizes, int n_in,
                              void* d_out, int out_size, void* d_ws, size_t ws_size,
                              hipStream_t stream) {
  const float* xy = (const float*)d_in[0];
  const float* U  = (const float*)d_in[1];
  const float* W1 = (const float*)d_in[2];
  const float* b1 = (const float*)d_in[3];
  const float* W2 = (const float*)d_in[4];
  const float* b2 = (const float*)d_in[5];
  const float* W3 = (const float*)d_in[6];
  const float* b3 = (const float*)d_in[7];
  const float* W4 = (const float*)d_in[8];
  const float* b4 = (const float*)d_in[9];
  const float* W5 = (const float*)d_in[10];
  const float* b5 = (const float*)d_in[11];
  unsigned short* ws = (unsigned short*)d_ws;   // needs ~102 KB
  float* out = (float*)d_out;

  prep_kernel<<<198, 256, 0, stream>>>(W1, b1, W2, W3, W4, W5, ws);
  mlp_kernel<<<GRID, 256, 0, stream>>>(xy, U, b2, b3, b4, b5, ws, out);
}

// Round 7
// 220.480 us; speedup vs baseline: 1.6733x; 1.6733x over previous
//
#include <hip/hip_runtime.h>
#include <hip/hip_bf16.h>

#define NPTS  1048576
#define GRID  512
#define NTILE 8192   // NPTS / 128
#define C2    2.8853900817779268f   // 2*log2(e)

typedef __attribute__((ext_vector_type(8))) short  s16x8;
typedef __attribute__((ext_vector_type(4))) float  f32x4;

__device__ __forceinline__ unsigned short bf16r(float v) {
  unsigned u = __builtin_bit_cast(unsigned, v);
  return (unsigned short)((u + 0x7fffu + ((u >> 16) & 1u)) >> 16);
}
__device__ __forceinline__ unsigned pack_bf16x2(float lo, float hi) {
  __hip_bfloat162 h = __float22bfloat162_rn(float2{lo, hi});
  unsigned r;
  __builtin_memcpy(&r, &h, sizeof(r));
  return r;
}
// tanh(s) with bias pre-folded: bc = bias*C2
__device__ __forceinline__ float tanh_e(float acc, float bc) {
  float e = __builtin_amdgcn_exp2f(fmaf(acc, C2, bc));
  return 1.0f - 2.0f * __builtin_amdgcn_rcpf(1.0f + e);
}
__device__ __forceinline__ float sigm_fast(float x) {
  return __builtin_amdgcn_rcpf(1.0f + __builtin_amdgcn_exp2f(x * -1.4426950408889634f));
}
// k' permutation: position k' holds original column n_orig(k')
__device__ __forceinline__ int n_orig(int kp) {
  return ((kp >> 1) & 3) * 32 + (kp & 1) * 16 + (kp >> 3);
}

// ws layout (u16 units):
//  [0 .. 49152)     : Wt images: ws[m*16384 + n*128 + k'] = bf16(W[n_orig(k')][n]), m=0..2 (W2,W3,W4)
//  [49152 .. 49920) : 384 floats: w1x[128], w1y[128], b1[128] in k'-order
//  [49920 .. 50944) : b5f image: ws[49920 + kt*512 + lane*8 + e]
__global__ void prep_kernel(const float* __restrict__ W1, const float* __restrict__ b1,
                            const float* __restrict__ W2, const float* __restrict__ W3,
                            const float* __restrict__ W4, const float* __restrict__ W5,
                            unsigned short* __restrict__ ws)
{
  int tid = blockIdx.x * 256 + threadIdx.x;
  if (tid < 49152) {
    int m   = tid >> 14;
    int idx = tid & 16383;
    int n   = idx >> 7;
    int kp  = idx & 127;
    int k   = n_orig(kp);
    const float* W = (m == 0) ? W2 : (m == 1) ? W3 : W4;
    ws[(m << 14) + n * 128 + kp] = bf16r(W[k * 128 + n]);
  } else if (tid < 49536) {
    int i = tid - 49152;                 // 0..383
    float* wsf = (float*)(ws + 49152);
    int kp = i & 127;
    int j  = n_orig(kp);
    float v;
    if (i < 128)      v = W1[j];
    else if (i < 256) v = W1[128 + j];
    else              v = b1[j];
    wsf[i] = v;
  } else if (tid < 50560) {
    int idx = tid - 49536;               // 0..1023
    int e  = idx & 7;
    int l  = (idx >> 3) & 63;
    int kt = idx >> 9;
    int lg = l >> 4, lnl = l & 15;
    int no = ((e >> 1) & 3) * 32 + (e & 1) * 16 + kt * 4 + lg;
    unsigned short v = 0;
    if (lnl < 2) v = bf16r(W5[no * 2 + lnl]);
    ws[49920 + kt * 512 + l * 8 + e] = v;
  }
}

__global__ __launch_bounds__(256, 2)
void mlp_kernel(const float* __restrict__ xy, const float* __restrict__ Uin,
                const float* __restrict__ b2, const float* __restrict__ b3,
                const float* __restrict__ b4, const float* __restrict__ b5,
                const unsigned short* __restrict__ ws, float* __restrict__ out)
{
  // ping-pong h buffers: 128 rows x 128 k' bf16 each
  __shared__ __align__(16) unsigned char hbuf0[32768];
  __shared__ __align__(16) unsigned char hbuf1[32768];

  const int tid  = threadIdx.x;
  const int lane = tid & 63;
  const int wid  = tid >> 6;   // 0..3 : column group of 32
  const int lg   = lane >> 4;  // 0..3
  const int ln   = lane & 15;
  const int c0   = tid & 15;   // layer-1 k'-chunk

  const float Uval = Uin[0];
  const float b5v  = (ln < 2) ? b5[ln] : 0.0f;

  // biases (folded with C2) for this thread's two columns per layer
  float bcr[3][2];
#pragma unroll
  for (int nt = 0; nt < 2; ++nt) {
    int n = wid * 32 + nt * 16 + ln;
    bcr[0][nt] = b2[n] * C2;
    bcr[1][nt] = b3[n] * C2;
    bcr[2][nt] = b4[n] * C2;
  }

  // layer-1 weights for this thread's k'-chunk c0
  const float* wsf = (const float*)(ws + 49152);
  float w1x[8], w1y[8], b1r[8];
#pragma unroll
  for (int t = 0; t < 8; ++t) {
    w1x[t] = wsf[c0 * 8 + t];
    w1y[t] = wsf[128 + c0 * 8 + t];
    b1r[t] = wsf[256 + c0 * 8 + t];
  }

  // ---- register-resident weights: loaded ONCE per block ----
  s16x8 Bf[3][2][4];
#pragma unroll
  for (int l = 0; l < 3; ++l)
#pragma unroll
    for (int nt = 0; nt < 2; ++nt) {
      int n = wid * 32 + nt * 16 + ln;
#pragma unroll
      for (int kt = 0; kt < 4; ++kt)
        Bf[l][nt][kt] = *(const s16x8*)(ws + l * 16384 + n * 128 + kt * 32 + lg * 8);
    }
  s16x8 b5f[4];
#pragma unroll
  for (int kt = 0; kt < 4; ++kt)
    b5f[kt] = *(const s16x8*)(ws + 49920 + kt * 512 + lane * 8);

  // ---- hoisted LDS byte-address bases (swizzle folded in) ----
  // A-read: row = mt*16+ln -> row&7 == ln&7 (const per thread)
  const unsigned aBase = (unsigned)(ln * 256) + ((unsigned)(lg * 16) ^ ((unsigned)(ln & 7) << 4));
  // write: row = mt*16 + lg*4 + r -> row&7 == (lg*4+r)&7 (const per thread per r)
  unsigned wBase[4];
#pragma unroll
  for (int r = 0; r < 4; ++r) {
    int rr = lg * 4 + r;
    wBase[r] = (unsigned)(rr * 256) + ((unsigned)(ln * 16 + wid * 4) ^ ((unsigned)(rr & 7) << 4));
  }
  // layer-1 write: p = i*16 + (tid>>4) -> p&7 == (tid>>4)&7 (const per thread)
  const unsigned l1Base = (unsigned)((tid >> 4) * 256) +
                          ((unsigned)(c0 * 16) ^ ((unsigned)((tid >> 4) & 7) << 4));

  for (int tile = blockIdx.x; tile < NTILE; tile += GRID) {
    const int pbase = tile << 7;

    // ---- layer 1: h1 = tanh(xy@W1+b1) -> hbuf0 ----
#pragma unroll
    for (int i = 0; i < 8; ++i) {
      int p = i * 16 + (tid >> 4);
      float2 v = ((const float2*)xy)[pbase + p];
      unsigned q[4];
#pragma unroll
      for (int t2 = 0; t2 < 4; ++t2) {
        float s0 = fmaf(v.x, w1x[2 * t2],     fmaf(v.y, w1y[2 * t2],     b1r[2 * t2]));
        float s1 = fmaf(v.x, w1x[2 * t2 + 1], fmaf(v.y, w1y[2 * t2 + 1], b1r[2 * t2 + 1]));
        float e0 = __builtin_amdgcn_exp2f(s0 * C2);
        float e1 = __builtin_amdgcn_exp2f(s1 * C2);
        float h0 = 1.0f - 2.0f * __builtin_amdgcn_rcpf(1.0f + e0);
        float h1 = 1.0f - 2.0f * __builtin_amdgcn_rcpf(1.0f + e1);
        q[t2] = pack_bf16x2(h0, h1);
      }
      *(uint4*)(hbuf0 + l1Base + i * 4096) = uint4{q[0], q[1], q[2], q[3]};
    }
    __syncthreads();   // h1 visible

    // ---- layers 2..4: read buf[l&1], write the other; write immediately ----
#pragma unroll
    for (int l = 0; l < 3; ++l) {
      const unsigned char* bufR = (l & 1) ? hbuf1 : hbuf0;
      unsigned char*       bufW = (l & 1) ? hbuf0 : hbuf1;
#pragma unroll
      for (int mt = 0; mt < 8; ++mt) {
        s16x8 A[4];
#pragma unroll
        for (int kt = 0; kt < 4; ++kt)
          A[kt] = *(const s16x8*)(bufR + aBase + mt * 4096 + kt * 64);
        f32x4 acc0 = f32x4{0.f, 0.f, 0.f, 0.f};
        f32x4 acc1 = f32x4{0.f, 0.f, 0.f, 0.f};
#pragma unroll
        for (int kt = 0; kt < 4; ++kt) {
          acc0 = __builtin_amdgcn_mfma_f32_16x16x32_bf16(A[kt], Bf[l][0][kt], acc0, 0, 0, 0);
          acc1 = __builtin_amdgcn_mfma_f32_16x16x32_bf16(A[kt], Bf[l][1][kt], acc1, 0, 0, 0);
        }
#pragma unroll
        for (int r = 0; r < 4; ++r) {
          float t0 = tanh_e(acc0[r], bcr[l][0]);
          float t1 = tanh_e(acc1[r], bcr[l][1]);
          *(unsigned*)(bufW + wBase[r] + mt * 4096) = pack_bf16x2(t0, t1);
        }
      }
      __syncthreads();   // layer outputs visible; bufR free for reuse
    }

    // ---- layer 5 + epilogue (reads hbuf1 = L4 out; each wave: 32 rows) ----
    f32x4 acc5[2];
#pragma unroll
    for (int m5 = 0; m5 < 2; ++m5) acc5[m5] = f32x4{0.f, 0.f, 0.f, 0.f};
#pragma unroll
    for (int m5 = 0; m5 < 2; ++m5)
#pragma unroll
      for (int kt = 0; kt < 4; ++kt) {
        s16x8 a = *(const s16x8*)(hbuf1 + aBase + wid * 8192 + m5 * 4096 + kt * 64);
        acc5[m5] = __builtin_amdgcn_mfma_f32_16x16x32_bf16(a, b5f[kt], acc5[m5], 0, 0, 0);
      }
    if (ln < 2) {
#pragma unroll
      for (int m5 = 0; m5 < 2; ++m5)
#pragma unroll
        for (int r = 0; r < 4; ++r) {
          int p = pbase + wid * 32 + m5 * 16 + lg * 4 + r;
          float uh = acc5[m5][r] + b5v;
          float2 v = ((const float2*)xy)[p];
          float Bm = v.x * (1.0f - v.x) * v.y * (1.0f - v.y);
          if (ln == 0) {
            float psi = sigm_fast(50.0f * (v.x - 0.05f)) * sigm_fast(50.0f * (0.95f - v.x));
            out[p] = Uval * v.y * psi + Bm * uh;
          } else {
            out[NPTS + p] = Bm * uh;
          }
        }
    }
    // no trailing barrier needed: next tile's layer-1 writes hbuf0, whose last
    // readers (layer 4) are behind the l=2 __syncthreads; layer-5 reads hbuf1.
  }
}

extern "C" void kernel_launch(void* const* d_in, const int* in_sizes, int n_in,
                              void* d_out, int out_size, void* d_ws, size_t ws_size,
                              hipStream_t stream) {
  const float* xy = (const float*)d_in[0];
  const float* U  = (const float*)d_in[1];
  const float* W1 = (const float*)d_in[2];
  const float* b1 = (const float*)d_in[3];
  const float* W2 = (const float*)d_in[4];
  const float* b2 = (const float*)d_in[5];
  const float* W3 = (const float*)d_in[6];
  const float* b3 = (const float*)d_in[7];
  const float* W4 = (const float*)d_in[8];
  const float* b4 = (const float*)d_in[9];
  const float* W5 = (const float*)d_in[10];
  const float* b5 = (const float*)d_in[11];
  unsigned short* ws = (unsigned short*)d_ws;   // needs ~102 KB
  float* out = (float*)d_out;

  prep_kernel<<<198, 256, 0, stream>>>(W1, b1, W2, W3, W4, W5, ws);
  mlp_kernel<<<GRID, 256, 0, stream>>>(xy, U, b2, b3, b4, b5, ws, out);
}

// Round 8
// 206.453 us; speedup vs baseline: 1.7870x; 1.0679x over previous
//
#include <hip/hip_runtime.h>
#include <hip/hip_bf16.h>

#define NPTS  1048576
#define GRID  512
#define NTILE 8192   // NPTS / 128
#define C2    2.8853900817779268f   // 2*log2(e)

typedef __attribute__((ext_vector_type(8))) short  s16x8;
typedef __attribute__((ext_vector_type(4))) float  f32x4;

__device__ __forceinline__ unsigned short bf16r(float v) {
  unsigned u = __builtin_bit_cast(unsigned, v);
  return (unsigned short)((u + 0x7fffu + ((u >> 16) & 1u)) >> 16);
}
__device__ __forceinline__ unsigned pack_bf16x2(float lo, float hi) {
  __hip_bfloat162 h = __float22bfloat162_rn(float2{lo, hi});
  unsigned r;
  __builtin_memcpy(&r, &h, sizeof(r));
  return r;
}
// tanh(s) with bias pre-folded: bc = bias*C2
__device__ __forceinline__ float tanh_e(float acc, float bc) {
  float e = __builtin_amdgcn_exp2f(fmaf(acc, C2, bc));
  return 1.0f - 2.0f * __builtin_amdgcn_rcpf(1.0f + e);
}
__device__ __forceinline__ float sigm_fast(float x) {
  return __builtin_amdgcn_rcpf(1.0f + __builtin_amdgcn_exp2f(x * -1.4426950408889634f));
}

// ws layout (u16 units) — W stored TRANSPOSED as MFMA A-fragments (natural n order):
//  [0 .. 49152)     : ws[((l*8 + nbg)*4 + kt)*512 + lane*8 + e] =
//                     bf16( W_{l+2}[k*128 + n] ), k = kt*32 + (lane>>4)*8 + e,
//                     n = nbg*16 + (lane&15);  l=0..2 (W2,W3,W4)
//  [49152 .. 49664) : W5 A-frag image: ws[49152 + kt*512 + lane*8 + e] =
//                     (lane&15)<2 ? bf16(W5[k*2 + (lane&15)]) : 0
__global__ void prep_kernel(const float* __restrict__ W2, const float* __restrict__ W3,
                            const float* __restrict__ W4, const float* __restrict__ W5,
                            unsigned short* __restrict__ ws)
{
  int tid = blockIdx.x * 256 + threadIdx.x;
  if (tid < 49152) {
    int l    = tid >> 14;
    int idx  = tid & 16383;
    int e    = idx & 7;
    int lane = (idx >> 3) & 63;
    int kt   = (idx >> 9) & 3;
    int nbg  = (idx >> 11) & 7;
    int k = kt * 32 + (lane >> 4) * 8 + e;
    int n = nbg * 16 + (lane & 15);
    const float* W = (l == 0) ? W2 : (l == 1) ? W3 : W4;
    ws[tid] = bf16r(W[k * 128 + n]);
  } else if (tid < 49664) {
    int idx  = tid - 49152;
    int e    = idx & 7;
    int lane = (idx >> 3) & 63;
    int kt   = idx >> 9;
    int k  = kt * 32 + (lane >> 4) * 8 + e;
    int nl = lane & 15;
    ws[tid] = (nl < 2) ? bf16r(W5[k * 2 + nl]) : (unsigned short)0;
  }
}

__global__ __launch_bounds__(256, 2)
void mlp_kernel(const float* __restrict__ xy, const float* __restrict__ Uin,
                const float* __restrict__ W1, const float* __restrict__ b1,
                const float* __restrict__ b2, const float* __restrict__ b3,
                const float* __restrict__ b4, const float* __restrict__ b5,
                const unsigned short* __restrict__ ws, float* __restrict__ out)
{
  // ping-pong h buffers: 128 rows (points) x 128 cols (natural n) bf16
  __shared__ __align__(16) unsigned char hbuf0[32768];
  __shared__ __align__(16) unsigned char hbuf1[32768];

  const int tid  = threadIdx.x;
  const int lane = tid & 63;
  const int wid  = tid >> 6;   // 0..3 : n-column group of 32
  const int lg   = lane >> 4;  // 0..3
  const int ln   = lane & 15;
  const int c0   = tid & 15;   // layer-1 n-chunk

  const float Uval = Uin[0];
  const float b50  = b5[0];
  const float b51  = b5[1];

  // biases (folded with C2): n = wid*32 + nb*16 + lg*4 + r
  float bcr[3][2][4];
#pragma unroll
  for (int nb = 0; nb < 2; ++nb)
#pragma unroll
    for (int r = 0; r < 4; ++r) {
      int n = wid * 32 + nb * 16 + lg * 4 + r;
      bcr[0][nb][r] = b2[n] * C2;
      bcr[1][nb][r] = b3[n] * C2;
      bcr[2][nb][r] = b4[n] * C2;
    }

  // layer-1 weights for this thread's n-chunk c0 (natural order, straight from global)
  float w1x[8], w1y[8], b1r[8];
#pragma unroll
  for (int t = 0; t < 8; ++t) {
    w1x[t] = W1[c0 * 8 + t];
    w1y[t] = W1[128 + c0 * 8 + t];
    b1r[t] = b1[c0 * 8 + t];
  }

  // ---- register-resident weight A-fragments, loaded ONCE ----
  s16x8 Wa[3][2][4];
#pragma unroll
  for (int l = 0; l < 3; ++l)
#pragma unroll
    for (int nb = 0; nb < 2; ++nb)
#pragma unroll
      for (int kt = 0; kt < 4; ++kt)
        Wa[l][nb][kt] = *(const s16x8*)(ws + (((l * 8 + wid * 2 + nb) * 4 + kt) << 9) + lane * 8);
  s16x8 b5f[4];
#pragma unroll
  for (int kt = 0; kt < 4; ++kt)
    b5f[kt] = *(const s16x8*)(ws + 49152 + kt * 512 + lane * 8);

  // ---- hoisted LDS byte bases (row swizzle: byte ^= (row&7)<<4) ----
  // B-frag read: row = mt*16+ln, col16B-chunk = kt*64 + lg*16
  const unsigned rBase = (unsigned)(ln * 256) + ((unsigned)(lg * 16) ^ ((unsigned)(ln & 7) << 4));
  // C write: row = mt*16+ln, col bytes = wid*64 + nb*32 + lg*8 (8B, conflict-free)
  unsigned wBase[2];
#pragma unroll
  for (int nb = 0; nb < 2; ++nb)
    wBase[nb] = (unsigned)(ln * 256) +
                ((unsigned)(wid * 64 + nb * 32 + lg * 8) ^ ((unsigned)(ln & 7) << 4));
  // layer-1 write: row p = i*16 + (tid>>4), col = c0*16
  const unsigned l1Base = (unsigned)((tid >> 4) * 256) +
                          ((unsigned)(c0 * 16) ^ ((unsigned)((tid >> 4) & 7) << 4));

  for (int tile = blockIdx.x; tile < NTILE; tile += GRID) {
    const int pbase = tile << 7;

    // ---- layer 1: h1 = tanh(xy@W1+b1) -> hbuf0 (natural n order) ----
#pragma unroll
    for (int i = 0; i < 8; ++i) {
      int p = i * 16 + (tid >> 4);
      float2 v = ((const float2*)xy)[pbase + p];
      unsigned q[4];
#pragma unroll
      for (int t2 = 0; t2 < 4; ++t2) {
        float s0 = fmaf(v.x, w1x[2 * t2],     fmaf(v.y, w1y[2 * t2],     b1r[2 * t2]));
        float s1 = fmaf(v.x, w1x[2 * t2 + 1], fmaf(v.y, w1y[2 * t2 + 1], b1r[2 * t2 + 1]));
        float e0 = __builtin_amdgcn_exp2f(s0 * C2);
        float e1 = __builtin_amdgcn_exp2f(s1 * C2);
        float h0 = 1.0f - 2.0f * __builtin_amdgcn_rcpf(1.0f + e0);
        float h1 = 1.0f - 2.0f * __builtin_amdgcn_rcpf(1.0f + e1);
        q[t2] = pack_bf16x2(h0, h1);
      }
      *(uint4*)(hbuf0 + l1Base + i * 4096) = uint4{q[0], q[1], q[2], q[3]};
    }
    __syncthreads();   // h1 visible

    // ---- layers 2..4: D = W^T · h^T  (weights are the A operand) ----
#pragma unroll
    for (int l = 0; l < 3; ++l) {
      const unsigned char* bufR = (l & 1) ? hbuf1 : hbuf0;
      unsigned char*       bufW = (l & 1) ? hbuf0 : hbuf1;
#pragma unroll
      for (int mt = 0; mt < 8; ++mt) {
        s16x8 B[4];
#pragma unroll
        for (int kt = 0; kt < 4; ++kt)
          B[kt] = *(const s16x8*)(bufR + rBase + mt * 4096 + kt * 64);
        f32x4 acc0 = f32x4{0.f, 0.f, 0.f, 0.f};
        f32x4 acc1 = f32x4{0.f, 0.f, 0.f, 0.f};
#pragma unroll
        for (int kt = 0; kt < 4; ++kt) {
          acc0 = __builtin_amdgcn_mfma_f32_16x16x32_bf16(Wa[l][0][kt], B[kt], acc0, 0, 0, 0);
          acc1 = __builtin_amdgcn_mfma_f32_16x16x32_bf16(Wa[l][1][kt], B[kt], acc1, 0, 0, 0);
        }
        // lane holds 4 consecutive n for one point p=mt*16+ln -> single b64 write
        {
          float t0 = tanh_e(acc0[0], bcr[l][0][0]);
          float t1 = tanh_e(acc0[1], bcr[l][0][1]);
          float t2 = tanh_e(acc0[2], bcr[l][0][2]);
          float t3 = tanh_e(acc0[3], bcr[l][0][3]);
          *(uint2*)(bufW + wBase[0] + mt * 4096) = uint2{pack_bf16x2(t0, t1), pack_bf16x2(t2, t3)};
        }
        {
          float t0 = tanh_e(acc1[0], bcr[l][1][0]);
          float t1 = tanh_e(acc1[1], bcr[l][1][1]);
          float t2 = tanh_e(acc1[2], bcr[l][1][2]);
          float t3 = tanh_e(acc1[3], bcr[l][1][3]);
          *(uint2*)(bufW + wBase[1] + mt * 4096) = uint2{pack_bf16x2(t0, t1), pack_bf16x2(t2, t3)};
        }
      }
      __syncthreads();
    }

    // ---- layer 5 + epilogue (reads hbuf1 = L4 out; wave: 32 points) ----
    f32x4 acc5[2];
#pragma unroll
    for (int m5 = 0; m5 < 2; ++m5) acc5[m5] = f32x4{0.f, 0.f, 0.f, 0.f};
#pragma unroll
    for (int m5 = 0; m5 < 2; ++m5)
#pragma unroll
      for (int kt = 0; kt < 4; ++kt) {
        s16x8 b = *(const s16x8*)(hbuf1 + rBase + wid * 8192 + m5 * 4096 + kt * 64);
        acc5[m5] = __builtin_amdgcn_mfma_f32_16x16x32_bf16(b5f[kt], b, acc5[m5], 0, 0, 0);
      }
    if (lg == 0) {
      // lane (ln, lg=0) holds n5=0 (u_hat, r=0) and n5=1 (v_hat, r=1) for p=...+ln
#pragma unroll
      for (int m5 = 0; m5 < 2; ++m5) {
        int p = pbase + wid * 32 + m5 * 16 + ln;
        float uh = acc5[m5][0] + b50;
        float vh = acc5[m5][1] + b51;
        float2 v = ((const float2*)xy)[p];
        float Bm = v.x * (1.0f - v.x) * v.y * (1.0f - v.y);
        float psi = sigm_fast(50.0f * (v.x - 0.05f)) * sigm_fast(50.0f * (0.95f - v.x));
        out[p]        = fmaf(Uval * v.y, psi, Bm * uh);
        out[NPTS + p] = Bm * vh;
      }
    }
    // no trailing barrier needed: next layer-1 writes hbuf0; its last readers
    // (layer 4) are behind the l=2 barrier; layer-5 reads hbuf1 only.
  }
}

extern "C" void kernel_launch(void* const* d_in, const int* in_sizes, int n_in,
                              void* d_out, int out_size, void* d_ws, size_t ws_size,
                              hipStream_t stream) {
  const float* xy = (const float*)d_in[0];
  const float* U  = (const float*)d_in[1];
  const float* W1 = (const float*)d_in[2];
  const float* b1 = (const float*)d_in[3];
  const float* W2 = (const float*)d_in[4];
  const float* b2 = (const float*)d_in[5];
  const float* W3 = (const float*)d_in[6];
  const float* b3 = (const float*)d_in[7];
  const float* W4 = (const float*)d_in[8];
  const float* b4 = (const float*)d_in[9];
  const float* W5 = (const float*)d_in[10];
  const float* b5 = (const float*)d_in[11];
  unsigned short* ws = (unsigned short*)d_ws;   // needs ~97 KB
  float* out = (float*)d_out;

  prep_kernel<<<194, 256, 0, stream>>>(W2, W3, W4, W5, ws);
  mlp_kernel<<<GRID, 256, 0, stream>>>(xy, U, W1, b1, b2, b3, b4, b5, ws, out);
}